// Round 9
// baseline (572.551 us; speedup 1.0000x reference)
//
#include <hip/hip_runtime.h>
#include <hip/hip_bf16.h>
#include <math.h>

#define HIDDEN 1280
#define HEADS 16
#define HD 80           // head dim
#define HALF 40
#define BB 2
#define NN 2048
#define MROWS (BB * NN) // 4096
// 1/sqrt(80) * log2(e): scores come out in log2 domain -> exp2 directly
#define QSCALE ((float)(0.11180339887498949 * 1.4426950408889634))

typedef __attribute__((ext_vector_type(8))) _Float16 f16x8;
typedef __attribute__((ext_vector_type(4))) float f32x4;

#define AS1 __attribute__((address_space(1)))
#define AS3 __attribute__((address_space(3)))

// Split fp32 into fp16 hi + fp16 lo (hi+lo carries ~22 mantissa bits).
__device__ __forceinline__ void splitf16(float x, ushort& hi, ushort& lo) {
    _Float16 h = (_Float16)x;
    _Float16 l = (_Float16)(x - (float)h);
    hi = __builtin_bit_cast(ushort, h);
    lo = __builtin_bit_cast(ushort, l);
}

__device__ __forceinline__ ushort f2h(float x) {
    _Float16 h = (_Float16)x;
    return __builtin_bit_cast(ushort, h);
}

// ---------------------------------------------------------------------------
// Elementwise split: fp32 [n] -> fp16 hi[n], lo[n]. 4 elems/thread.
// ---------------------------------------------------------------------------
__global__ __launch_bounds__(256) void split_f16_kernel(
    const float* __restrict__ in, ushort* __restrict__ hi,
    ushort* __restrict__ lo, int n4)
{
    int i = blockIdx.x * 256 + threadIdx.x;
    if (i >= n4) return;
    float4 v = ((const float4*)in)[i];
    ushort4 h, l;
    splitf16(v.x, h.x, l.x);
    splitf16(v.y, h.y, l.y);
    splitf16(v.z, h.z, l.z);
    splitf16(v.w, h.w, l.w);
    ((ushort4*)hi)[i] = h;
    ((ushort4*)lo)[i] = l;
}

// ---------------------------------------------------------------------------
// Transpose to fp16: W[K][N] fp32 -> WT[N][K] fp16 (single plane).
// ---------------------------------------------------------------------------
__global__ __launch_bounds__(256) void tsplit_f16_kernel(
    const float* __restrict__ W, ushort* __restrict__ T, int K, int N)
{
    __shared__ float s[32][33];
    const int n0 = blockIdx.x * 32;
    const int k0 = blockIdx.y * 32;
    {
        int tn = threadIdx.x & 31, tk = threadIdx.x >> 5;
        #pragma unroll
        for (int i = 0; i < 4; ++i)
            s[tk + i * 8][tn] = W[(size_t)(k0 + tk + i * 8) * N + n0 + tn];
    }
    __syncthreads();
    {
        int tk = threadIdx.x & 31, tn = threadIdx.x >> 5;
        #pragma unroll
        for (int i = 0; i < 4; ++i)
            T[(size_t)(n0 + tn + i * 8) * K + k0 + tk] = f2h(s[tk][tn + i * 8]);
    }
}

// ---------------------------------------------------------------------------
// fp16x2 MFMA GEMM, double-buffered, single barrier per K-iter.
// C[M,N] = (Ahi+Alo)[M,K] @ B[N,K]^T + bias[N]
// Block: 128 x BNT (BNT=256 or 128). 4 waves (2x2); wave tile 64 x BNT/2.
// LDS/buf: Ahi(128x32) Alo(128x32) B(BNTx32) fp16. 2 buffers.
// Loop: barrier -> issue stage(t+1) into buf^1 -> compute(t); the prefetch
// flies during compute so the next barrier's vmcnt drain is ~free.
// ---------------------------------------------------------------------------
#define BM 128
#define BK 32

template<int BNT>
__global__ __launch_bounds__(256, 2) void gemm_f16x2_db_kernel(
    const ushort* __restrict__ Ahi, const ushort* __restrict__ Alo,
    const ushort* __restrict__ Bh,
    const float* __restrict__ bias, float* __restrict__ C,
    int M, int N, int K)
{
    constexpr int JT = BNT / 32;                 // b-frag tiles per wave
    constexpr int BUFSZ = 8192 + BNT * 32;       // ushorts per buffer
    constexpr int NSEG = 16 + BNT / 16;          // 1KB segments per buffer
    __shared__ __align__(16) ushort lds[2 * BUFSZ];

    const int tid = threadIdx.x;
    const int wid = tid >> 6;
    const int lane = tid & 63;
    const int col0 = blockIdx.x * BNT;
    const int row0 = blockIdx.y * BM;
    const int wy = wid >> 1, wx = wid & 1;
    const int lrow = lane >> 2;
    const int lchunk = lane & 3;
    const int nT = K / BK;

    f32x4 acc[4][JT] = {};

    auto stage = [&](int t, int buf) {
        ushort* base = lds + buf * BUFSZ;
        const int k0 = t * BK;
        #pragma unroll
        for (int i = 0; i < (NSEG + 3) / 4; ++i) {
            int s = wid + i * 4;
            if (s >= NSEG) break;
            // tiles: [0,8)=Ahi, [8,16)=Alo, [16,NSEG)=B
            const ushort* src = (s < 8) ? Ahi : (s < 16) ? Alo : Bh;
            int tile = (s < 8) ? 0 : (s < 16) ? 1 : 2;
            int tseg = s - tile * 8;             // for B: s-16
            int srow = (tile < 2) ? row0 : col0;
            int trow = (tile == 2) ? (s - 16) * 16 : tseg * 16;
            const ushort* g = src + (size_t)(srow + trow + lrow) * K + k0 + lchunk * 8;
            ushort* l = base + tile * 4096 + (tile == 2 ? (s - 16) : tseg) * 512 + lane * 8;
            __builtin_amdgcn_global_load_lds(
                (const AS1 unsigned int*)g, (AS3 unsigned int*)l, 16, 0, 0);
        }
    };

    stage(0, 0);

    for (int t = 0; t < nT; ++t) {
        __syncthreads();                         // stage(t) landed; buf reuse safe
        if (t + 1 < nT) stage(t + 1, (t + 1) & 1);

        const ushort* base = lds + (t & 1) * BUFSZ;
        const int q = lane >> 4;
        const int r = lane & 15;
        f16x8 ah[4], al[4], bf[JT];
        #pragma unroll
        for (int i = 0; i < 4; ++i) {
            int arow = wy * 64 + i * 16 + r;
            ah[i] = *(const f16x8*)(base + 0 * 4096 + arow * 32 + q * 8);
            al[i] = *(const f16x8*)(base + 1 * 4096 + arow * 32 + q * 8);
        }
        #pragma unroll
        for (int j = 0; j < JT; ++j) {
            int brow = wx * (BNT / 2) + j * 16 + r;
            bf[j] = *(const f16x8*)(base + 8192 + brow * 32 + q * 8);
        }
        #pragma unroll
        for (int i = 0; i < 4; ++i) {
            #pragma unroll
            for (int j = 0; j < JT; ++j) {
                acc[i][j] = __builtin_amdgcn_mfma_f32_16x16x32_f16(al[i], bf[j], acc[i][j], 0, 0, 0);
                acc[i][j] = __builtin_amdgcn_mfma_f32_16x16x32_f16(ah[i], bf[j], acc[i][j], 0, 0, 0);
            }
        }
    }

    const int q = lane >> 4, r = lane & 15;
    #pragma unroll
    for (int i = 0; i < 4; ++i) {
        #pragma unroll
        for (int j = 0; j < JT; ++j) {
            int col = col0 + wx * (BNT / 2) + j * 16 + r;
            float b = bias[col];
            #pragma unroll
            for (int v = 0; v < 4; ++v) {
                int row = row0 + wy * 64 + i * 16 + q * 4 + v;
                C[(size_t)row * N + col] = acc[i][j][v] + b;
            }
        }
    }
}

// ---------------------------------------------------------------------------
// RoPE + scale + fp16 convert + head-major relayout.
// Reads qkv fp32 (b,n,3,H,80). Writes:
//   qf [bh][n][96] fp16 (RoPE'd, * QSCALE, d 80..95 zeroed)
//   kf [bh][n][96] fp16 (RoPE'd, d 80..95 zeroed)
//   vt [bh][80][2048] fp16 (V transposed)
// Grid (NN/64, HEADS, BB), 256 threads.
// ---------------------------------------------------------------------------
__global__ __launch_bounds__(256) void rope_split_kernel(
    const float* __restrict__ qkv, const float* __restrict__ cos_t,
    const float* __restrict__ sin_t,
    ushort* __restrict__ qf, ushort* __restrict__ kf,
    ushort* __restrict__ vt)
{
    __shared__ float s_v[64][84];
    const int tid = threadIdx.x;
    const int b = blockIdx.z, h = blockIdx.y;
    const int n0 = blockIdx.x * 64;
    const int bh = b * HEADS + h;

    // V tile -> LDS (coalesced float4 loads)
    #pragma unroll
    for (int i = 0; i < 5; ++i) {
        int u = tid + i * 256;
        int n = u / 20, c = u % 20;
        const float* src = qkv + (size_t)(b * NN + n0 + n) * 3840 + 2 * HIDDEN + h * HD + c * 4;
        *(float4*)(&s_v[n][c * 4]) = *(const float4*)src;
    }

    // q,k RoPE + fp16: 640 units, each = (token n, 4-wide d group in [0,40))
    for (int u = tid; u < 640; u += 256) {
        int n = u / 10, p = u % 10;
        int d = p * 4;
        int ng = n0 + n;
        size_t rowb = (size_t)(b * NN + ng) * 3840;
        float4 c0 = *(const float4*)(cos_t + ng * HD + d);
        float4 c1 = *(const float4*)(cos_t + ng * HD + d + HALF);
        float4 s0 = *(const float4*)(sin_t + ng * HD + d);
        float4 s1 = *(const float4*)(sin_t + ng * HD + d + HALF);
        size_t qo = ((size_t)bh * NN + ng) * 96;
        // q (scaled by QSCALE so scores are in log2 domain)
        {
            float4 x0 = *(const float4*)(qkv + rowb + h * HD + d);
            float4 x1 = *(const float4*)(qkv + rowb + h * HD + d + HALF);
            ushort4 h4a, h4b;
            h4a.x = f2h((x0.x * c0.x - x1.x * s0.x) * QSCALE);
            h4a.y = f2h((x0.y * c0.y - x1.y * s0.y) * QSCALE);
            h4a.z = f2h((x0.z * c0.z - x1.z * s0.z) * QSCALE);
            h4a.w = f2h((x0.w * c0.w - x1.w * s0.w) * QSCALE);
            h4b.x = f2h((x1.x * c1.x + x0.x * s1.x) * QSCALE);
            h4b.y = f2h((x1.y * c1.y + x0.y * s1.y) * QSCALE);
            h4b.z = f2h((x1.z * c1.z + x0.z * s1.z) * QSCALE);
            h4b.w = f2h((x1.w * c1.w + x0.w * s1.w) * QSCALE);
            *(ushort4*)(qf + qo + d) = h4a;
            *(ushort4*)(qf + qo + d + HALF) = h4b;
        }
        // k (unscaled)
        {
            float4 x0 = *(const float4*)(qkv + rowb + HIDDEN + h * HD + d);
            float4 x1 = *(const float4*)(qkv + rowb + HIDDEN + h * HD + d + HALF);
            ushort4 h4a, h4b;
            h4a.x = f2h(x0.x * c0.x - x1.x * s0.x);
            h4a.y = f2h(x0.y * c0.y - x1.y * s0.y);
            h4a.z = f2h(x0.z * c0.z - x1.z * s0.z);
            h4a.w = f2h(x0.w * c0.w - x1.w * s0.w);
            h4b.x = f2h(x1.x * c1.x + x0.x * s1.x);
            h4b.y = f2h(x1.y * c1.y + x0.y * s1.y);
            h4b.z = f2h(x1.z * c1.z + x0.z * s1.z);
            h4b.w = f2h(x1.w * c1.w + x0.w * s1.w);
            *(ushort4*)(kf + qo + d) = h4a;
            *(ushort4*)(kf + qo + d + HALF) = h4b;
        }
    }

    // zero the d=80..95 pad for q and k. 256 units: which(1b) x n(6b) x part(1b)
    {
        int which = tid >> 7;
        int u = tid & 127;
        int n = u >> 1, part = u & 1;
        size_t o = ((size_t)bh * NN + n0 + n) * 96 + 80 + part * 8;
        uint4 z = {0u, 0u, 0u, 0u};
        if (which == 0) *(uint4*)(qf + o) = z;
        else            *(uint4*)(kf + o) = z;
    }
    __syncthreads();

    // V^T write (fp16): unit = (d, 16-token chunk)
    for (int u = tid; u < 320; u += 256) {
        int d = u >> 2, nc = u & 3;
        ushort hs[16];
        #pragma unroll
        for (int kk = 0; kk < 16; ++kk)
            hs[kk] = f2h(s_v[nc * 16 + kk][d]);
        size_t o = ((size_t)bh * HD + d) * NN + n0 + nc * 16;
        uint4 w0, w1;
        w0.x = (uint)hs[0] | ((uint)hs[1] << 16);
        w0.y = (uint)hs[2] | ((uint)hs[3] << 16);
        w0.z = (uint)hs[4] | ((uint)hs[5] << 16);
        w0.w = (uint)hs[6] | ((uint)hs[7] << 16);
        w1.x = (uint)hs[8] | ((uint)hs[9] << 16);
        w1.y = (uint)hs[10] | ((uint)hs[11] << 16);
        w1.z = (uint)hs[12] | ((uint)hs[13] << 16);
        w1.w = (uint)hs[14] | ((uint)hs[15] << 16);
        *(uint4*)(vt + o) = w0;
        *(uint4*)(vt + o + 8) = w1;
    }
}

// ---------------------------------------------------------------------------
// MFMA flash attention v4 (round-8 verbatim): fp16 single-term QK + PV.
// ---------------------------------------------------------------------------
__global__ __launch_bounds__(256, 2) void attn_mfma_kernel(
    const ushort* __restrict__ qf, const ushort* __restrict__ kf,
    const ushort* __restrict__ vt,
    ushort* __restrict__ ao_hi, ushort* __restrict__ ao_lo)
{
    __shared__ __align__(16) ushort lds[20480];   // 40960 B
    ushort* k_s = lds;                            // [64][96] = 6144
    _Float16* v_s = (_Float16*)(lds + 6144);      // [80][64] chunk-swizzled
    _Float16* p_s = (_Float16*)(lds + 11264);     // [128][64] block-swizzled

    const int tid = threadIdx.x;
    const int wave = tid >> 6, lane = tid & 63;
    const int quad = lane >> 4, r = lane & 15;
    const int b = blockIdx.z, h = blockIdx.y;
    const int bh = b * HEADS + h;
    const int q0 = blockIdx.x * 128;

    // Q a-frags from [bh][n][96] fp16 (pre-scaled by QSCALE, pad zero)
    f16x8 qfr[2][3];
    #pragma unroll
    for (int mt = 0; mt < 2; ++mt)
        #pragma unroll
        for (int c = 0; c < 3; ++c) {
            size_t o = ((size_t)bh * NN + q0 + wave * 32 + mt * 16 + r) * 96 + c * 32 + quad * 8;
            qfr[mt][c] = *(const f16x8*)(qf + o);
        }

    f32x4 oacc[2][5] = {};
    float l_part[2][4] = {};

    const size_t kb = (size_t)bh * NN * 96;
    const size_t vb = (size_t)bh * HD * NN;

    for (int j0 = 0; j0 < NN; j0 += 64) {
        __syncthreads();
        // stage K fp16 (12 segs, linear) + V^T fp16 (10 segs, src-swizzled)
        for (int s = wave; s < 22; s += 4) {
            if (s < 12) {
                int off = s * 512 + lane * 8;
                __builtin_amdgcn_global_load_lds(
                    (const AS1 unsigned int*)(kf + kb + (size_t)j0 * 96 + off),
                    (AS3 unsigned int*)(k_s + off), 16, 0, 0);
            } else {
                int ts = s - 12;
                int off = ts * 512 + lane * 8;
                size_t go = vb + (size_t)(ts * 8 + (lane >> 3)) * NN + j0
                          + (size_t)(((lane & 7) ^ (lane >> 3)) * 8);
                __builtin_amdgcn_global_load_lds(
                    (const AS1 unsigned int*)(vt + go),
                    (AS3 unsigned int*)((ushort*)v_s + off), 16, 0, 0);
            }
        }
        __syncthreads();

        // QK^T -> scores in C-layout (log2 domain), single fp16 term
        f32x4 sc[2][4] = {};
        #pragma unroll
        for (int jt = 0; jt < 4; ++jt) {
            f16x8 kbf[3];
            int j = jt * 16 + r;
            #pragma unroll
            for (int c = 0; c < 3; ++c)
                kbf[c] = *(const f16x8*)(k_s + j * 96 + c * 32 + quad * 8);
            #pragma unroll
            for (int mt = 0; mt < 2; ++mt)
                #pragma unroll
                for (int c = 0; c < 3; ++c)
                    sc[mt][jt] = __builtin_amdgcn_mfma_f32_16x16x32_f16(qfr[mt][c], kbf[c], sc[mt][jt], 0, 0, 0);
        }

        // no-max softmax: p = exp2(s); P -> LDS fp16 (swizzled); l partials
        #pragma unroll
        for (int mt = 0; mt < 2; ++mt) {
            #pragma unroll
            for (int v = 0; v < 4; ++v) {
                float ps = 0.0f;
                #pragma unroll
                for (int jt = 0; jt < 4; ++jt) {
                    float p = __builtin_amdgcn_exp2f(sc[mt][jt][v]);
                    sc[mt][jt][v] = p;
                    ps += p;
                }
                l_part[mt][v] += ps;
            }
            int rowbase = wave * 32 + mt * 16 + quad * 4;
            #pragma unroll
            for (int jt = 0; jt < 4; ++jt) {
                int bks = (jt * 2 + (r >> 3)) ^ (quad << 1);
                #pragma unroll
                for (int v = 0; v < 4; ++v)
                    p_s[(rowbase + v) * 64 + bks * 8 + (r & 7)] = (_Float16)sc[mt][jt][v];
            }
        }

        // P a-frags (wave-private rows, swizzled reads)
        f16x8 pa[2][2];
        #pragma unroll
        for (int mt = 0; mt < 2; ++mt)
            #pragma unroll
            for (int cc = 0; cc < 2; ++cc) {
                int rowp = wave * 32 + mt * 16 + r;
                int bks = (cc * 4 + quad) ^ (((r >> 2) & 3) << 1);
                pa[mt][cc] = *(const f16x8*)(p_s + rowp * 64 + bks * 8);
            }

        // PV with V^T b-frags (chunk-swizzled reads)
        #pragma unroll
        for (int dt = 0; dt < 5; ++dt)
            #pragma unroll
            for (int cc = 0; cc < 2; ++cc) {
                int ck = (cc * 4 + quad) ^ (r & 7);
                f16x8 vbf = *(const f16x8*)(v_s + (dt * 16 + r) * 64 + ck * 8);
                oacc[0][dt] = __builtin_amdgcn_mfma_f32_16x16x32_f16(pa[0][cc], vbf, oacc[0][dt], 0, 0, 0);
                oacc[1][dt] = __builtin_amdgcn_mfma_f32_16x16x32_f16(pa[1][cc], vbf, oacc[1][dt], 0, 0, 0);
            }
    }

    // deferred l reduction (across the 16 r-lanes of each quad)
    float inv_l[2][4];
    #pragma unroll
    for (int mt = 0; mt < 2; ++mt)
        #pragma unroll
        for (int v = 0; v < 4; ++v) {
            float l = l_part[mt][v];
            l += __shfl_xor(l, 1);
            l += __shfl_xor(l, 2);
            l += __shfl_xor(l, 4);
            l += __shfl_xor(l, 8);
            inv_l[mt][v] = 1.0f / l;
        }

    // epilogue: normalize + fp16-split into LDS [128][80] hi/lo, uint4 stores
    __syncthreads();
    #pragma unroll
    for (int mt = 0; mt < 2; ++mt)
        #pragma unroll
        for (int v = 0; v < 4; ++v) {
            int row = wave * 32 + mt * 16 + quad * 4 + v;
            #pragma unroll
            for (int dt = 0; dt < 5; ++dt) {
                float o = oacc[mt][dt][v] * inv_l[mt][v];
                ushort hh, ll;
                splitf16(o, hh, ll);
                lds[row * 80 + dt * 16 + r] = hh;
                lds[10240 + row * 80 + dt * 16 + r] = ll;
            }
        }
    __syncthreads();
    {
        size_t gbase = ((size_t)b * NN + q0) * HIDDEN + h * HD;
        #pragma unroll
        for (int i = 0; i < 10; ++i) {
            int u = tid + i * 256;            // 0..2559
            int plane = u / 1280, idx = u % 1280;
            int row = idx / 10, part = idx % 10;
            uint4 w = *(const uint4*)(lds + plane * 10240 + idx * 8);
            ushort* dst = (plane ? ao_lo : ao_hi) + gbase + (size_t)row * HIDDEN + part * 8;
            *(uint4*)dst = w;
        }
    }
}

// ---------------------------------------------------------------------------
extern "C" void kernel_launch(void* const* d_in, const int* in_sizes, int n_in,
                              void* d_out, int out_size, void* d_ws, size_t ws_size,
                              hipStream_t stream)
{
    const float* x      = (const float*)d_in[0];
    const float* cos_t  = (const float*)d_in[1];
    const float* sin_t  = (const float*)d_in[2];
    const float* qkv_w  = (const float*)d_in[3];
    const float* qkv_b  = (const float*)d_in[4];
    const float* proj_w = (const float*)d_in[5];
    const float* proj_b = (const float*)d_in[6];
    float* out = (float*)d_out;

    char* ws = (char*)d_ws;
    // layout (bytes), phase-based reuse:
    //   [0, 62914560)           qkv fp32 (gemm1 out; dead after rope_split)
    //       -> ao_hi @0 (10485760), ao_lo @10485760 (attn out, fp16 hi/lo)
    //   [62914560, 72744960)    wT fp16 (qkv_w^T); after gemm1:
    //       -> vt fp16 @62914560 (10485760, ends 73400320)
    //       -> re-written by tsplit_f16(proj_w) AFTER attention (3276800)
    //   [82575360, 103546880)   x split fp16 hi/lo (gemm1 A); after gemm1:
    //       -> qf @83886080 (12582912), kf @96468992 (ends 109051904)
    float*  qkv   = (float*)ws;
    ushort* ao_hi = (ushort*)ws;
    ushort* ao_lo = (ushort*)(ws + 10485760);
    ushort* wT    = (ushort*)(ws + 62914560);
    ushort* vt    = (ushort*)(ws + 62914560);
    ushort* a_hi  = (ushort*)(ws + 82575360);
    ushort* a_lo  = (ushort*)(ws + 93061120);
    ushort* q_f   = (ushort*)(ws + 83886080);
    ushort* k_f   = (ushort*)(ws + 96468992);

    // 1) split x into fp16 hi/lo
    split_f16_kernel<<<(MROWS * HIDDEN / 4 + 255) / 256, 256, 0, stream>>>(
        x, a_hi, a_lo, MROWS * HIDDEN / 4);

    // 2) transpose qkv_w -> fp16
    tsplit_f16_kernel<<<dim3(3 * HIDDEN / 32, HIDDEN / 32), 256, 0, stream>>>(
        qkv_w, wT, HIDDEN, 3 * HIDDEN);

    // 3) qkv = x @ qkv_w + qkv_b   (fp16x2 MFMA, dbuf, 256-wide blocks)
    gemm_f16x2_db_kernel<256><<<dim3(3 * HIDDEN / 256, MROWS / BM), 256, 0, stream>>>(
        a_hi, a_lo, wT, qkv_b, qkv, MROWS, 3 * HIDDEN, HIDDEN);

    // 4) RoPE + fp16 relayout (overwrites wT and x-split regions — both dead)
    rope_split_kernel<<<dim3(NN / 64, HEADS, BB), 256, 0, stream>>>(
        qkv, cos_t, sin_t, q_f, k_f, vt);

    // 5) MFMA flash attention (ao overwrites qkv region — dead now)
    attn_mfma_kernel<<<dim3(NN / 128, HEADS, BB), 256, 0, stream>>>(
        q_f, k_f, vt, ao_hi, ao_lo);

    // 6) transpose proj_w -> fp16 (overwrites vt region — dead after attn)
    tsplit_f16_kernel<<<dim3(HIDDEN / 32, HIDDEN / 32), 256, 0, stream>>>(
        proj_w, wT, HIDDEN, HIDDEN);

    // 7) out = attn_out @ proj_w + proj_b   (fp16x2 MFMA, dbuf, 128-wide)
    gemm_f16x2_db_kernel<128><<<dim3(HIDDEN / 128, MROWS / BM), 256, 0, stream>>>(
        ao_hi, ao_lo, wT, proj_b, out, MROWS, HIDDEN, HIDDEN);
}